// Round 16
// baseline (123.680 us; speedup 1.0000x reference)
//
#include <hip/hip_runtime.h>

#define H 1024
#define W 1024
#define NB 8
#define TY 16
#define NT 256
#define WCOLS 256           /* output cols per wave */
#define LW (WCOLS + 8)      /* 264: 4-col halo each side */
#define RS 10               /* ring slots (distance 9 + 1) */

__global__ void ncc_zero(double* acc) { *acc = 0.0; }

__global__ void ncc_finalize(const double* __restrict__ acc, float* __restrict__ out) {
    out[0] = 1.0f - (float)(*acc * (1.0 / 8388608.0));  // 8*1024*1024 pixels
}

// pack 2 f32 -> u32 of 2 bf16 (lo [15:0], hi [31:16]), RNE
__device__ __forceinline__ unsigned pk2(float lo, float hi) {
    unsigned r;
    asm("v_cvt_pk_bf16_f32 %0, %1, %2" : "=v"(r) : "v"(lo), "v"(hi));
    return r;
}
__device__ __forceinline__ float ulo(unsigned u) { return __uint_as_float(u << 16); }
__device__ __forceinline__ float uhi(unsigned u) { return __uint_as_float(u & 0xffff0000u); }

__global__ __launch_bounds__(NT) void ncc_main(
    const float* __restrict__ Jg,  // y_pred
    const float* __restrict__ Ig,  // y_true
    double* __restrict__ acc)
{
    __shared__ uint4    ring[RS][NT];     // bf16-packed rows {i01,i23,j01,j23}: 40 KB
    __shared__ unsigned ringH[RS][32];    // halo cols {iH,jH} packed: 1.25 KB
    __shared__ float    vs[NT / 64][5][LW]; // vertical sums I,J,II,JJ,IJ: 21.1 KB
    __shared__ double   sred[NT / 64];

    const int n     = blockIdx.x;
    const int b     = n & 7;       // image index == XCD (locality: 1 image per XCD)
    const int strip = n >> 3;
    const int y0    = strip * TY;
    const int t     = threadIdx.x;
    const int w     = t >> 6;
    const int lane  = t & 63;
    const int xw    = lane << 2;
    const int x0    = (w << 8) + xw;

    const float* __restrict__ Ib = Ig + (size_t)b * (H * W);
    const float* __restrict__ Jb = Jg + (size_t)b * (H * W);

    // halo: lanes 0..3 left halo cols, 4..7 right halo cols (one scalar col each)
    const int   wbase = w << 8;
    const bool  isH   = (lane < 8);
    const int   hcv   = (lane < 4) ? (wbase - 4 + lane) : (wbase + WCOLS + (lane - 4));
    const float mh    = (isH && (unsigned)hcv < (unsigned)W) ? 1.0f : 0.0f;
    const int   hcc   = min(max(hcv, 0), W - 1);
    const int   hslot = (lane < 4) ? lane : (WCOLS + lane);
    const int   hidx  = (w << 3) + lane;   // valid for lane<8

    float sI[4]={0,0,0,0}, sJ[4]={0,0,0,0}, sII[4]={0,0,0,0}, sJJ[4]={0,0,0,0}, sIJ[4]={0,0,0,0};
    float hs0=0, hs1=0, hs2=0, hs3=0, hs4=0;

#define FDECL(nm) float4 nm##i, nm##j; float nm##hI, nm##hJ, nm##m;
#define FLOAD(nm, yy) do {                                                          \
        const int r_ = (yy);                                                        \
        nm##m = ((unsigned)r_ < (unsigned)H) ? 1.0f : 0.0f;                         \
        const int rc_ = min(max(r_, 0), H - 1);                                     \
        const float* pI_ = Ib + (size_t)rc_ * W;                                    \
        const float* pJ_ = Jb + (size_t)rc_ * W;                                    \
        nm##i = *(const float4*)(pI_ + x0);                                         \
        nm##j = *(const float4*)(pJ_ + x0);                                         \
        nm##hI = 0.f; nm##hJ = 0.f;                                                 \
        if (isH) { nm##hI = pI_[hcc]; nm##hJ = pJ_[hcc]; }                          \
    } while (0)

// fold 5 packed u32s into running sums with sign SG (+1 enter / -1 leave); exact cancel
#define FOLDU(u0, u1, u2, u3, u4, SG) do {                                          \
        const float i0_=ulo(u0), i1_=uhi(u0), i2_=ulo(u1), i3_=uhi(u1);             \
        const float j0_=ulo(u2), j1_=uhi(u2), j2_=ulo(u3), j3_=uhi(u3);             \
        const float hA_=ulo(u4), hB_=uhi(u4);                                       \
        sI[0]=fmaf(SG,i0_,sI[0]); sI[1]=fmaf(SG,i1_,sI[1]);                         \
        sI[2]=fmaf(SG,i2_,sI[2]); sI[3]=fmaf(SG,i3_,sI[3]);                         \
        sJ[0]=fmaf(SG,j0_,sJ[0]); sJ[1]=fmaf(SG,j1_,sJ[1]);                         \
        sJ[2]=fmaf(SG,j2_,sJ[2]); sJ[3]=fmaf(SG,j3_,sJ[3]);                         \
        sII[0]=fmaf(SG,i0_*i0_,sII[0]); sII[1]=fmaf(SG,i1_*i1_,sII[1]);             \
        sII[2]=fmaf(SG,i2_*i2_,sII[2]); sII[3]=fmaf(SG,i3_*i3_,sII[3]);             \
        sJJ[0]=fmaf(SG,j0_*j0_,sJJ[0]); sJJ[1]=fmaf(SG,j1_*j1_,sJJ[1]);             \
        sJJ[2]=fmaf(SG,j2_*j2_,sJJ[2]); sJJ[3]=fmaf(SG,j3_*j3_,sJJ[3]);             \
        sIJ[0]=fmaf(SG,i0_*j0_,sIJ[0]); sIJ[1]=fmaf(SG,i1_*j1_,sIJ[1]);             \
        sIJ[2]=fmaf(SG,i2_*j2_,sIJ[2]); sIJ[3]=fmaf(SG,i3_*j3_,sIJ[3]);             \
        hs0=fmaf(SG,hA_,hs0); hs1=fmaf(SG,hB_,hs1);                                 \
        hs2=fmaf(SG,hA_*hA_,hs2); hs3=fmaf(SG,hB_*hB_,hs3);                         \
        hs4=fmaf(SG,hA_*hB_,hs4);                                                   \
    } while (0)

// pack f-set nm, write to ring slot, fold(+) from the packed (bf16) values
#define PACKW(slot, nm) do {                                                        \
        const float m_ = nm##m;                                                     \
        const unsigned e0_ = pk2(nm##i.x * m_, nm##i.y * m_);                       \
        const unsigned e1_ = pk2(nm##i.z * m_, nm##i.w * m_);                       \
        const unsigned e2_ = pk2(nm##j.x * m_, nm##j.y * m_);                       \
        const unsigned e3_ = pk2(nm##j.z * m_, nm##j.w * m_);                       \
        const unsigned e4_ = pk2(nm##hI * (m_ * mh), nm##hJ * (m_ * mh));           \
        ring[slot][t] = make_uint4(e0_, e1_, e2_, e3_);                             \
        if (isH) ringH[slot][hidx] = e4_;                                           \
        FOLDU(e0_, e1_, e2_, e3_, e4_, 1.0f);                                       \
    } while (0)

// read ring slot, fold(-) — zero global traffic
#define LEAVE(slot) do {                                                            \
        const uint4 L_ = ring[slot][t];                                             \
        unsigned L4_ = 0u;                                                          \
        if (isH) L4_ = ringH[slot][hidx];                                           \
        FOLDU(L_.x, L_.y, L_.z, L_.w, L4_, -1.0f);                                  \
    } while (0)

#define PUB() do {                                                                  \
        *(float4*)&vs[w][0][4 + xw] = make_float4(sI[0],  sI[1],  sI[2],  sI[3]);   \
        *(float4*)&vs[w][1][4 + xw] = make_float4(sJ[0],  sJ[1],  sJ[2],  sJ[3]);   \
        *(float4*)&vs[w][2][4 + xw] = make_float4(sII[0], sII[1], sII[2], sII[3]);  \
        *(float4*)&vs[w][3][4 + xw] = make_float4(sJJ[0], sJJ[1], sJJ[2], sJJ[3]);  \
        *(float4*)&vs[w][4][4 + xw] = make_float4(sIJ[0], sIJ[1], sIJ[2], sIJ[3]);  \
        if (isH) {                                                                  \
            vs[w][0][hslot] = hs0; vs[w][1][hslot] = hs1; vs[w][2][hslot] = hs2;    \
            vs[w][3][hslot] = hs3; vs[w][4][hslot] = hs4;                           \
        }                                                                           \
    } while (0)

#define HTAP(a, cg, T, o) do {                                                      \
        float s_ = a.x + a.y + a.z + a.w + cg.x + T;                                \
        o[0] = s_; s_ += cg.y - a.x;                                                \
        o[1] = s_; s_ += cg.z - a.y;                                                \
        o[2] = s_; s_ += cg.w - a.z;                                                \
        o[3] = s_;                                                                  \
    } while (0)

#define HALO_READ()                                                                        \
        float4 a0_ = *(const float4*)&vs[w][0][xw], c0_ = *(const float4*)&vs[w][0][xw + 8]; \
        float4 a1_ = *(const float4*)&vs[w][1][xw], c1_ = *(const float4*)&vs[w][1][xw + 8]; \
        float4 a2_ = *(const float4*)&vs[w][2][xw], c2_ = *(const float4*)&vs[w][2][xw + 8]; \
        float4 a3_ = *(const float4*)&vs[w][3][xw], c3_ = *(const float4*)&vs[w][3][xw + 8]; \
        float4 a4_ = *(const float4*)&vs[w][4][xw], c4_ = *(const float4*)&vs[w][4][xw + 8];

#define CCROW(TI, TJ, TII, TJJ, TIJ) do {                                           \
        float h0[4], h1[4], h2[4], h3[4], h4[4];                                    \
        HTAP(a0_, c0_, TI, h0); HTAP(a1_, c1_, TJ, h1); HTAP(a2_, c2_, TII, h2);    \
        HTAP(a3_, c3_, TJJ, h3); HTAP(a4_, c4_, TIJ, h4);                           \
        _Pragma("unroll")                                                           \
        for (int c = 0; c < 4; ++c) {                                               \
            const float uI    = h0[c] * inv;                                        \
            const float uJ    = h1[c] * inv;                                        \
            const float cross = h4[c] * inv - uI * uJ;                              \
            const float Iv    = h2[c] * inv - uI * uI;                              \
            const float Jv    = h3[c] * inv - uJ * uJ;                              \
            accv += cross * rsqrtf(fmaxf(Iv * Jv, 1e-7f));                          \
        }                                                                           \
    } while (0)

    // ---- init: rows y0-4..y0+4 -> ring slots 0..8, folded(+); distance-2 load pipe ----
    FDECL(f0) FDECL(f1)
    FLOAD(f0, y0 - 4); FLOAD(f1, y0 - 3);
    PACKW(0, f0); FLOAD(f0, y0 - 2);
    PACKW(1, f1); FLOAD(f1, y0 - 1);
    PACKW(2, f0); FLOAD(f0, y0    );
    PACKW(3, f1); FLOAD(f1, y0 + 1);
    PACKW(4, f0); FLOAD(f0, y0 + 2);
    PACKW(5, f1); FLOAD(f1, y0 + 3);
    PACKW(6, f0); FLOAD(f0, y0 + 4);
    PACKW(7, f1);
    PACKW(8, f0);

    // ---- prologue: publish window(y0); prefetch enter rows (distance-2 sets A/B) ----
    PUB();
    asm volatile("" ::: "memory");
    FDECL(pA) FDECL(pB)
    FLOAD(pA, y0 + 5);
    FLOAD(pB, y0 + 6);

    const float inv = 1.0f / 81.0f;
    float accv = 0.0f;

// iter k (k=0..14): halo-read window(y0+k) -> T -> leave(ring k%10) -> enter(pack P,
// write slot (9+k)%10, fold) -> publish window(y0+k+1) -> refill P -> cc row y0+k
#define ITER(k, P, RF) do {                                                         \
        HALO_READ();                                                                \
        asm volatile("" ::: "memory");                                              \
        const float T0 = sI[0]  + sI[1]  + sI[2]  + sI[3];                          \
        const float T1 = sJ[0]  + sJ[1]  + sJ[2]  + sJ[3];                          \
        const float T2 = sII[0] + sII[1] + sII[2] + sII[3];                         \
        const float T3 = sJJ[0] + sJJ[1] + sJJ[2] + sJJ[3];                         \
        const float T4 = sIJ[0] + sIJ[1] + sIJ[2] + sIJ[3];                         \
        LEAVE((k) % RS);                                                            \
        PACKW((9 + (k)) % RS, P);                                                   \
        PUB();                                                                      \
        asm volatile("" ::: "memory");                                              \
        RF;                                                                         \
        CCROW(T0, T1, T2, T3, T4);                                                  \
    } while (0)

    ITER(0,  pA, FLOAD(pA, y0 + 7));
    ITER(1,  pB, FLOAD(pB, y0 + 8));
    ITER(2,  pA, FLOAD(pA, y0 + 9));
    ITER(3,  pB, FLOAD(pB, y0 + 10));
    ITER(4,  pA, FLOAD(pA, y0 + 11));
    ITER(5,  pB, FLOAD(pB, y0 + 12));
    ITER(6,  pA, FLOAD(pA, y0 + 13));
    ITER(7,  pB, FLOAD(pB, y0 + 14));
    ITER(8,  pA, FLOAD(pA, y0 + 15));
    ITER(9,  pB, FLOAD(pB, y0 + 16));
    ITER(10, pA, FLOAD(pA, y0 + 17));
    ITER(11, pB, FLOAD(pB, y0 + 18));
    ITER(12, pA, FLOAD(pA, y0 + 19));
    ITER(13, pB, (void)0);
    ITER(14, pA, (void)0);

    // final output row y0+15: read halos + cc only
    {
        HALO_READ();
        asm volatile("" ::: "memory");
        const float T0 = sI[0]  + sI[1]  + sI[2]  + sI[3];
        const float T1 = sJ[0]  + sJ[1]  + sJ[2]  + sJ[3];
        const float T2 = sII[0] + sII[1] + sII[2] + sII[3];
        const float T3 = sJJ[0] + sJJ[1] + sJJ[2] + sJJ[3];
        const float T4 = sIJ[0] + sIJ[1] + sIJ[2] + sIJ[3];
        CCROW(T0, T1, T2, T3, T4);
    }

#undef ITER
#undef CCROW
#undef HALO_READ
#undef HTAP
#undef PUB
#undef LEAVE
#undef PACKW
#undef FOLDU
#undef FLOAD
#undef FDECL

    // wave reduce (64 lanes) -> LDS -> one atomic per block (cold path)
    #pragma unroll
    for (int off = 32; off > 0; off >>= 1)
        accv += __shfl_down(accv, off);
    if (lane == 0)
        sred[w] = (double)accv;
    __syncthreads();
    if (t == 0) {
        double s = sred[0];
        #pragma unroll
        for (int q = 1; q < NT / 64; ++q) s += sred[q];
        atomicAdd(acc, s);
    }
}

extern "C" void kernel_launch(void* const* d_in, const int* in_sizes, int n_in,
                              void* d_out, int out_size, void* d_ws, size_t ws_size,
                              hipStream_t stream) {
    const float* y_pred = (const float*)d_in[0];  // Ji
    const float* y_true = (const float*)d_in[1];  // Ii
    float* out = (float*)d_out;
    double* accp = (double*)d_ws;

    ncc_zero<<<dim3(1), dim3(1), 0, stream>>>(accp);
    // 8 images x 64 strips = 512 blocks; image = blockIdx&7 (one image per XCD);
    // read-once global traffic (~101 MB), leave rows served from LDS ring
    ncc_main<<<dim3(NB * (H / TY)), dim3(NT), 0, stream>>>(y_pred, y_true, accp);
    ncc_finalize<<<dim3(1), dim3(1), 0, stream>>>(accp, out);
}

// Round 17
// 40.978 us; speedup vs baseline: 3.0182x; 3.0182x over previous
//
#include <hip/hip_runtime.h>

#define H 1024
#define W 1024
#define NB 8
#define TY 8
#define NT 512              /* 8 waves per block, 2 strips of TY rows */
#define WCOLS 256           /* output cols per wave */
#define LW (WCOLS + 8)      /* 264: 4-col halo each side */

__global__ void ncc_zero(double* acc) { *acc = 0.0; }

__global__ void ncc_finalize(const double* __restrict__ acc, float* __restrict__ out) {
    out[0] = 1.0f - (float)(*acc * (1.0 / 8388608.0));  // 8*1024*1024 pixels
}

__global__ __launch_bounds__(NT) void ncc_main(
    const float* __restrict__ Jg,  // y_pred
    const float* __restrict__ Ig,  // y_true
    double* __restrict__ acc)
{
    __shared__ float vs[NT / 64][5][LW];   // wave-private vertical sums: I,J,II,JJ,IJ
    __shared__ double sred[NT / 64];

    const int b    = blockIdx.x;
    const int t    = threadIdx.x;
    const int w    = t >> 6;               // 0..7
    const int lane = t & 63;
    const int ws   = w & 3;                // wave-in-strip: col panel
    const int y0   = (blockIdx.y * 2 + (w >> 2)) * TY;   // waves 0-3: strip A, 4-7: strip B
    const int xw   = lane << 2;            // within-wave col base (0..252)
    const int x0   = (ws << 8) + xw;       // global col

    const float* __restrict__ Ib = Ig + (size_t)b * (H * W);
    const float* __restrict__ Jb = Jg + (size_t)b * (H * W);

    // halo: lanes 0..3 left halo cols, lanes 4..7 right halo cols (one scalar col each)
    const int   wbase = ws << 8;
    const bool  isH   = (lane < 8);
    const int   hc    = (lane < 4) ? (wbase - 4 + lane) : (wbase + WCOLS + (lane - 4));
    const float mh    = (isH && (unsigned)hc < (unsigned)W) ? 1.0f : 0.0f;
    const int   hcc   = min(max(hc, 0), W - 1);
    const int   hslot = (lane < 4) ? lane : (WCOLS + lane);  // 0..3 / 260..263

    float sI[4]={0,0,0,0}, sJ[4]={0,0,0,0}, sII[4]={0,0,0,0}, sJJ[4]={0,0,0,0}, sIJ[4]={0,0,0,0};
    float hs0=0, hs1=0, hs2=0, hs3=0, hs4=0;

    // ---- pipelined init: rows y0-4 .. y0+4, one row ahead in flight ----
    float4 civ, cjv; float chi = 0, chj = 0, cm;
    {
        const int r  = y0 - 4;
        cm = ((unsigned)r < (unsigned)H) ? 1.0f : 0.0f;
        const int rc = min(max(r, 0), H - 1);
        civ = *(const float4*)(Ib + (size_t)rc * W + x0);
        cjv = *(const float4*)(Jb + (size_t)rc * W + x0);
        if (isH) { chi = Ib[(size_t)rc * W + hcc]; chj = Jb[(size_t)rc * W + hcc]; }
    }
    #pragma unroll 1
    for (int k = -4; k <= 4; ++k) {
        // prefetch next row (dummy re-load of last row on final iter)
        const int   rn  = y0 + ((k < 4) ? (k + 1) : 4);
        const float nm  = ((unsigned)(y0 + k + 1) < (unsigned)H) ? 1.0f : 0.0f;
        const int   rnc = min(max(rn, 0), H - 1);
        float4 niv = *(const float4*)(Ib + (size_t)rnc * W + x0);
        float4 njv = *(const float4*)(Jb + (size_t)rnc * W + x0);
        float  nhi = 0, nhj = 0;
        if (isH) { nhi = Ib[(size_t)rnc * W + hcc]; nhj = Jb[(size_t)rnc * W + hcc]; }

        // fold current row
        {
            const float fi[4] = {civ.x * cm, civ.y * cm, civ.z * cm, civ.w * cm};
            const float fj[4] = {cjv.x * cm, cjv.y * cm, cjv.z * cm, cjv.w * cm};
            #pragma unroll
            for (int c = 0; c < 4; ++c) {
                sI[c] += fi[c]; sJ[c] += fj[c];
                sII[c] += fi[c] * fi[c]; sJJ[c] += fj[c] * fj[c]; sIJ[c] += fi[c] * fj[c];
            }
            const float mm = cm * mh;
            const float hi = chi * mm, hj = chj * mm;
            hs0 += hi; hs1 += hj; hs2 += hi * hi; hs3 += hj * hj; hs4 += hi * hj;
        }
        civ = niv; cjv = njv; chi = nhi; chj = nhj; cm = nm;
    }

    // ---- prologue prefetch for the first slide (window y0 -> y0+1) ----
    float4 pia, pja, pis, pjs; float phia = 0, phja = 0, phis = 0, phjs = 0; float pma, pms;
    {
        const int ra = y0 + 5, rs = y0 - 4;
        pma = (ra < H) ? 1.0f : 0.0f;
        pms = (rs >= 0) ? 1.0f : 0.0f;
        const int rca = min(ra, H - 1), rcs = max(rs, 0);
        pia = *(const float4*)(Ib + (size_t)rca * W + x0);
        pja = *(const float4*)(Jb + (size_t)rca * W + x0);
        pis = *(const float4*)(Ib + (size_t)rcs * W + x0);
        pjs = *(const float4*)(Jb + (size_t)rcs * W + x0);
        if (isH) {
            phia = Ib[(size_t)rca * W + hcc]; phja = Jb[(size_t)rca * W + hcc];
            phis = Ib[(size_t)rcs * W + hcc]; phjs = Jb[(size_t)rcs * W + hcc];
        }
    }

    const float inv = 1.0f / 81.0f;
    float accv = 0.0f;

    #pragma unroll 1
    for (int y = y0; y < y0 + TY; ++y) {
        // 1) publish window(y)
        *(float4*)&vs[w][0][4 + xw] = make_float4(sI[0],  sI[1],  sI[2],  sI[3]);
        *(float4*)&vs[w][1][4 + xw] = make_float4(sJ[0],  sJ[1],  sJ[2],  sJ[3]);
        *(float4*)&vs[w][2][4 + xw] = make_float4(sII[0], sII[1], sII[2], sII[3]);
        *(float4*)&vs[w][3][4 + xw] = make_float4(sJJ[0], sJJ[1], sJJ[2], sJJ[3]);
        *(float4*)&vs[w][4][4 + xw] = make_float4(sIJ[0], sIJ[1], sIJ[2], sIJ[3]);
        if (isH) {
            vs[w][0][hslot] = hs0; vs[w][1][hslot] = hs1; vs[w][2][hslot] = hs2;
            vs[w][3][hslot] = hs3; vs[w][4][hslot] = hs4;
        }
        asm volatile("" ::: "memory");

        // 2) issue halo reads only (own cols stay in registers); in-wave DS is in-order
        float4 a0 = *(const float4*)&vs[w][0][xw], c0 = *(const float4*)&vs[w][0][xw + 8];
        float4 a1 = *(const float4*)&vs[w][1][xw], c1 = *(const float4*)&vs[w][1][xw + 8];
        float4 a2 = *(const float4*)&vs[w][2][xw], c2 = *(const float4*)&vs[w][2][xw + 8];
        float4 a3 = *(const float4*)&vs[w][3][xw], c3 = *(const float4*)&vs[w][3][xw + 8];
        float4 a4 = *(const float4*)&vs[w][4][xw], c4 = *(const float4*)&vs[w][4][xw + 8];
        asm volatile("" ::: "memory");

        // 3) snapshot own totals of window(y) before sliding
        const float T0 = sI[0]  + sI[1]  + sI[2]  + sI[3];
        const float T1 = sJ[0]  + sJ[1]  + sJ[2]  + sJ[3];
        const float T2 = sII[0] + sII[1] + sII[2] + sII[3];
        const float T3 = sJJ[0] + sJJ[1] + sJJ[2] + sJJ[3];
        const float T4 = sIJ[0] + sIJ[1] + sIJ[2] + sIJ[3];

        // 4) slide sums to window(y+1) using prefetched rows (covers the LDS round trip)
        {
            const float fa[4] = {pia.x * pma, pia.y * pma, pia.z * pma, pia.w * pma};
            const float ga[4] = {pja.x * pma, pja.y * pma, pja.z * pma, pja.w * pma};
            const float fs[4] = {pis.x * pms, pis.y * pms, pis.z * pms, pis.w * pms};
            const float gs[4] = {pjs.x * pms, pjs.y * pms, pjs.z * pms, pjs.w * pms};
            #pragma unroll
            for (int c = 0; c < 4; ++c) {
                sI[c]  += fa[c] - fs[c];
                sJ[c]  += ga[c] - gs[c];
                sII[c] += fa[c] * fa[c] - fs[c] * fs[c];
                sJJ[c] += ga[c] * ga[c] - gs[c] * gs[c];
                sIJ[c] += fa[c] * ga[c] - fs[c] * gs[c];
            }
            const float hia = phia * (pma * mh), hja = phja * (pma * mh);
            const float his = phis * (pms * mh), hjs = phjs * (pms * mh);
            hs0 += hia - his;
            hs1 += hja - hjs;
            hs2 += hia * hia - his * his;
            hs3 += hja * hja - hjs * hjs;
            hs4 += hia * hja - his * hjs;
        }

        // 5) prefetch rows for the next slide (window y+1 -> y+2)
        {
            const int ra = y + 6, rs = y - 3;
            pma = (ra < H) ? 1.0f : 0.0f;
            pms = (rs >= 0) ? 1.0f : 0.0f;
            const int rca = min(ra, H - 1), rcs = max(rs, 0);
            pia = *(const float4*)(Ib + (size_t)rca * W + x0);
            pja = *(const float4*)(Jb + (size_t)rca * W + x0);
            pis = *(const float4*)(Ib + (size_t)rcs * W + x0);
            pjs = *(const float4*)(Jb + (size_t)rcs * W + x0);
            if (isH) {
                phia = Ib[(size_t)rca * W + hcc]; phja = Jb[(size_t)rca * W + hcc];
                phis = Ib[(size_t)rcs * W + hcc]; phjs = Jb[(size_t)rcs * W + hcc];
            }
        }

        // 6) combine halo + own totals -> 9-tap sums; per-pixel cc for row y
        float h[5][4];
        {
            const float4 aa[5]  = {a0, a1, a2, a3, a4};
            const float4 cc4[5] = {c0, c1, c2, c3, c4};
            const float  TT[5]  = {T0, T1, T2, T3, T4};
            #pragma unroll
            for (int q = 0; q < 5; ++q) {
                const float4 a  = aa[q];
                const float4 cg = cc4[q];
                float s = a.x + a.y + a.z + a.w + cg.x + TT[q];
                h[q][0] = s; s += cg.y - a.x;
                h[q][1] = s; s += cg.z - a.y;
                h[q][2] = s; s += cg.w - a.z;
                h[q][3] = s;
            }
        }
        #pragma unroll
        for (int c = 0; c < 4; ++c) {
            const float uI    = h[0][c] * inv;
            const float uJ    = h[1][c] * inv;
            const float cross = h[4][c] * inv - uI * uJ;
            const float Iv    = h[2][c] * inv - uI * uI;
            const float Jv    = h[3][c] * inv - uJ * uJ;
            accv += cross * rsqrtf(fmaxf(Iv * Jv, 1e-7f));
        }
    }

    // wave reduce (64 lanes) -> LDS -> one atomic per block (cold path)
    #pragma unroll
    for (int off = 32; off > 0; off >>= 1)
        accv += __shfl_down(accv, off);
    if (lane == 0)
        sred[w] = (double)accv;
    __syncthreads();
    if (t == 0) {
        double s = sred[0];
        #pragma unroll
        for (int q = 1; q < NT / 64; ++q) s += sred[q];
        atomicAdd(acc, s);
    }
}

extern "C" void kernel_launch(void* const* d_in, const int* in_sizes, int n_in,
                              void* d_out, int out_size, void* d_ws, size_t ws_size,
                              hipStream_t stream) {
    const float* y_pred = (const float*)d_in[0];  // Ji
    const float* y_true = (const float*)d_in[1];  // Ii
    float* out = (float*)d_out;
    double* accp = (double*)d_ws;

    ncc_zero<<<dim3(1), dim3(1), 0, stream>>>(accp);
    // 8 x 64 = 512 blocks x 8 waves (2 strips/block); 42.3 KB LDS -> 3 blocks/CU
    // = 24 resident waves/CU at VGPR<=85; zero barriers in hot loop
    dim3 grid(NB, H / TY / 2);
    ncc_main<<<grid, dim3(NT), 0, stream>>>(y_pred, y_true, accp);
    ncc_finalize<<<dim3(1), dim3(1), 0, stream>>>(accp, out);
}